// Round 2
// baseline (299.774 us; speedup 1.0000x reference)
//
#include <hip/hip_runtime.h>

typedef short short8 __attribute__((ext_vector_type(8)));
typedef float f32x4 __attribute__((ext_vector_type(4)));

// bf16 bit helpers (RNE)
__device__ __forceinline__ short f2bf(float f) {
    union { float f; unsigned u; } c; c.f = f;
    unsigned r = c.u + 0x7fffu + ((c.u >> 16) & 1u);
    return (short)(r >> 16);
}
__device__ __forceinline__ float bf2f(short s) {
    union { unsigned u; float f; } c; c.u = ((unsigned)(unsigned short)s) << 16;
    return c.f;
}

// ---------------------------------------------------------------------------
// Sizes: B=8, C=512, H=8, D=64, N=1024, M1=K1=1536 (3C rows / split-K cols)
// ---------------------------------------------------------------------------

// Pack Wq/Wk/Wv into A2[1536][1536] = [Whi | Whi | Wlo] rows, plus bias2[1536].
__global__ void k_pack_w(const float* __restrict__ Wq, const float* __restrict__ Wk,
                         const float* __restrict__ Wv, const float* __restrict__ bq,
                         const float* __restrict__ bk, const float* __restrict__ bv,
                         short* __restrict__ A2, float* __restrict__ bias2) {
    int t = blockIdx.x * 256 + threadIdx.x;      // 98304 threads
    int m = t >> 6;
    int c8 = (t & 63) << 3;
    const float* src = (m < 512) ? (Wq + m * 512)
                     : (m < 1024 ? (Wk + (m - 512) * 512) : (Wv + (m - 1024) * 512));
    float4 v0 = *(const float4*)(src + c8);
    float4 v1 = *(const float4*)(src + c8 + 4);
    float f[8] = {v0.x, v0.y, v0.z, v0.w, v1.x, v1.y, v1.z, v1.w};
    short8 hi, lo;
#pragma unroll
    for (int j = 0; j < 8; ++j) {
        short h = f2bf(f[j]);
        hi[j] = h;
        lo[j] = f2bf(f[j] - bf2f(h));
    }
    short* rowp = A2 + (size_t)m * 1536;
    *(short8*)(rowp + c8)        = hi;
    *(short8*)(rowp + 512 + c8)  = hi;
    *(short8*)(rowp + 1024 + c8) = lo;
    if (t < 1536)
        bias2[t] = (t < 512) ? bq[t] : (t < 1024 ? bk[t - 512] : bv[t - 1024]);
}

// Transpose x[b][c][n] -> xT2[b][n][1536] = [xhi | xlo | xhi] (k-contiguous rows)
__global__ void k_prep_x(const float* __restrict__ x, short* __restrict__ xT2) {
    __shared__ float xs[64][65];
    int nt = blockIdx.x * 64, ct = blockIdx.y * 64, b = blockIdx.z;
    int t = threadIdx.x;
    const float* xb = x + ((size_t)b * 512 + ct) * 1024 + nt;
#pragma unroll
    for (int p = 0; p < 4; ++p) {
        int c = p * 16 + (t >> 4), n4 = (t & 15) * 4;
        float4 v = *(const float4*)(xb + (size_t)c * 1024 + n4);
        xs[c][n4] = v.x; xs[c][n4 + 1] = v.y; xs[c][n4 + 2] = v.z; xs[c][n4 + 3] = v.w;
    }
    __syncthreads();
    int nl = t >> 2, part = t & 3;
    short* rowp = xT2 + ((size_t)b * 1024 + nt + nl) * 1536;
#pragma unroll
    for (int g = 0; g < 2; ++g) {
        short8 hi, lo;
#pragma unroll
        for (int j = 0; j < 8; ++j) {
            float f = xs[part * 16 + g * 8 + j][nl];
            short h = f2bf(f);
            hi[j] = h; lo[j] = f2bf(f - bf2f(h));
        }
        int c = ct + part * 16 + g * 8;
        *(short8*)(rowp + c)        = hi;
        *(short8*)(rowp + 512 + c)  = lo;
        *(short8*)(rowp + 1024 + c) = hi;
    }
}

// Split-bf16 GEMM: qkv[b][m][n] = sum_k A2[m][k]*xT2[b][n][k] + bias2[m]  (fp32 out)
__global__ __launch_bounds__(256) void k_proj(const short* __restrict__ A2,
                                              const short* __restrict__ xT2,
                                              const float* __restrict__ bias2,
                                              float* __restrict__ qkv) {
    __shared__ short As[128 * 40];
    __shared__ short Bs[128 * 40];
    int t = threadIdx.x;
    int lane = t & 63, w = t >> 6;
    int lm = lane & 15, lq = lane >> 4;
    int wr = (w >> 1) * 64, wc = (w & 1) * 64;
    int mb = blockIdx.y * 128, nb = blockIdx.x * 128, b = blockIdx.z;
    const short* Ag = A2 + (size_t)mb * 1536;
    const short* Bg = xT2 + ((size_t)b * 1024 + nb) * 1536;
    f32x4 acc[4][4];
#pragma unroll
    for (int i = 0; i < 4; ++i)
#pragma unroll
        for (int j = 0; j < 4; ++j) acc[i][j] = {0.f, 0.f, 0.f, 0.f};
    int srow = t >> 2, scol = (t & 3) * 8;
    for (int k0 = 0; k0 < 1536; k0 += 32) {
        *(uint4*)&As[srow * 40 + scol]        = *(const uint4*)(Ag + (size_t)srow * 1536 + k0 + scol);
        *(uint4*)&As[(srow + 64) * 40 + scol] = *(const uint4*)(Ag + (size_t)(srow + 64) * 1536 + k0 + scol);
        *(uint4*)&Bs[srow * 40 + scol]        = *(const uint4*)(Bg + (size_t)srow * 1536 + k0 + scol);
        *(uint4*)&Bs[(srow + 64) * 40 + scol] = *(const uint4*)(Bg + (size_t)(srow + 64) * 1536 + k0 + scol);
        __syncthreads();
        short8 af[4], bfr[4];
#pragma unroll
        for (int mt = 0; mt < 4; ++mt)
            af[mt] = *(short8*)&As[(wr + mt * 16 + lm) * 40 + lq * 8];
#pragma unroll
        for (int nt = 0; nt < 4; ++nt)
            bfr[nt] = *(short8*)&Bs[(wc + nt * 16 + lm) * 40 + lq * 8];
#pragma unroll
        for (int mt = 0; mt < 4; ++mt)
#pragma unroll
            for (int nt = 0; nt < 4; ++nt)
                acc[mt][nt] = __builtin_amdgcn_mfma_f32_16x16x32_bf16(af[mt], bfr[nt], acc[mt][nt], 0, 0, 0);
        __syncthreads();
    }
#pragma unroll
    for (int mt = 0; mt < 4; ++mt)
#pragma unroll
        for (int reg = 0; reg < 4; ++reg) {
            int row = mb + wr + mt * 16 + lq * 4 + reg;
            float bias = bias2[row];
#pragma unroll
            for (int nt = 0; nt < 4; ++nt) {
                int col = nb + wc + nt * 16 + lm;
                qkv[((size_t)b * 1536 + row) * 1024 + col] = acc[mt][nt][reg] + bias;
            }
        }
}

// v rows -> bf16 (native [b][h][d][n] layout)
__global__ void k_vb(const float* __restrict__ qkv, short* __restrict__ vb) {
    size_t i8 = ((size_t)blockIdx.x * 256 + threadIdx.x) * 8;
    size_t b = i8 >> 19;
    size_t rem = i8 & 524287;
    const float* src = qkv + b * 1572864 + 1048576 + rem;
    float4 v0 = *(const float4*)src;
    float4 v1 = *(const float4*)(src + 4);
    short8 o;
    o[0] = f2bf(v0.x); o[1] = f2bf(v0.y); o[2] = f2bf(v0.z); o[3] = f2bf(v0.w);
    o[4] = f2bf(v1.x); o[5] = f2bf(v1.y); o[6] = f2bf(v1.z); o[7] = f2bf(v1.w);
    *(short8*)(vb + i8) = o;
}

// rel2[h][n][128] = [relhi(0:64) | rello(64:128)]
__global__ void k_prep_rel(const float* __restrict__ rel_h, const float* __restrict__ rel_w,
                           short* __restrict__ rel2) {
    int tid = blockIdx.x * 256 + threadIdx.x;   // 65536
    int h = tid >> 13;
    int rem = tid & 8191;
    int n = rem >> 3;
    int g = rem & 7;
    int hh = n & 31, ww = n >> 5;
    short8 hi, lo;
#pragma unroll
    for (int j = 0; j < 8; ++j) {
        int d = g * 8 + j;
        float f = rel_h[(h * 64 + d) * 32 + hh] + rel_w[(h * 64 + d) * 32 + ww];
        short hb = f2bf(f);
        hi[j] = hb; lo[j] = f2bf(f - bf2f(hb));
    }
    short* row = rel2 + ((size_t)h * 1024 + n) * 128;
    *(short8*)(row + g * 8) = hi;
    *(short8*)(row + 64 + g * 8) = lo;
}

// Transpose q,k head-tiles and split: q2[bh][n][128]=[qhi|qlo], k2 same for k.
__global__ void k_prep_qk(const float* __restrict__ qkv, short* __restrict__ q2,
                          short* __restrict__ k2) {
    __shared__ float qs[64][65];
    __shared__ float ks[64][65];
    int nt = blockIdx.x * 64, h = blockIdx.y, b = blockIdx.z;
    int t = threadIdx.x;
    const float* qg = qkv + ((size_t)b * 1536 + h * 64) * 1024 + nt;
    const float* kg = qkv + ((size_t)b * 1536 + 512 + h * 64) * 1024 + nt;
#pragma unroll
    for (int p = 0; p < 4; ++p) {
        int d = p * 16 + (t >> 4), n4 = (t & 15) * 4;
        float4 v = *(const float4*)(qg + (size_t)d * 1024 + n4);
        qs[d][n4] = v.x; qs[d][n4 + 1] = v.y; qs[d][n4 + 2] = v.z; qs[d][n4 + 3] = v.w;
        float4 u = *(const float4*)(kg + (size_t)d * 1024 + n4);
        ks[d][n4] = u.x; ks[d][n4 + 1] = u.y; ks[d][n4 + 2] = u.z; ks[d][n4 + 3] = u.w;
    }
    __syncthreads();
    int nl = t >> 2, part = t & 3;
    int n = nt + nl;
    size_t bh = (size_t)b * 8 + h;
    short* qrow = q2 + (bh * 1024 + n) * 128;
    short* krow = k2 + (bh * 1024 + n) * 128;
#pragma unroll
    for (int g = 0; g < 2; ++g) {
        int d0 = part * 16 + g * 8;
        short8 qhi, qlo, khi, klo;
#pragma unroll
        for (int j = 0; j < 8; ++j) {
            float fq = qs[d0 + j][nl];
            short hq = f2bf(fq);
            qhi[j] = hq; qlo[j] = f2bf(fq - bf2f(hq));
            float fk = ks[d0 + j][nl];
            short hk = f2bf(fk);
            khi[j] = hk; klo[j] = f2bf(fk - bf2f(hk));
        }
        *(short8*)(qrow + d0) = qhi;
        *(short8*)(qrow + 64 + d0) = qlo;
        *(short8*)(krow + d0) = khi;
        *(short8*)(krow + 64 + d0) = klo;
    }
}

// Flash attention with split-bf16 S: one block per (b,h,128-query tile).
// S = Ahi*Bhi + Alo*Bhi + Ahi*Blo over augmented dim 128 (A=[q|rel], B=[k|q]).
// Online softmax; P via wave-private LDS rows; out written transposed [d][m].
__global__ __launch_bounds__(256) void k_attn(const short* __restrict__ q2,
                                              const short* __restrict__ k2,
                                              const short* __restrict__ rel2,
                                              const short* __restrict__ vb,
                                              float* __restrict__ out) {
    __shared__ __align__(16) char pool[65536];
    short* kb_s  = (short*)pool;            // [64][264]  -> 33792 B
    short* v_s   = (short*)(pool + 33792);  // [64][72]   ->  9216 B
    short* p_s   = (short*)(pool + 43008);  // [128][72]  -> 18432 B
    float* red_s = (float*)(pool + 61440);  // [128]      ->   512 B
    short* qa_s  = (short*)pool;            // phase-0 alias: [128][256] = 65536 B

    int t = threadIdx.x;
    int lane = t & 63, w = t >> 6;
    int lm = lane & 15, lq = lane >> 4;
    int mt0 = blockIdx.x, h = blockIdx.y, b = blockIdx.z;
    size_t bh = (size_t)b * 8 + h;
    const short* q2b = q2 + bh * 1024 * 128;
    const short* k2b = k2 + bh * 1024 * 128;
    const short* relb = rel2 + (size_t)h * 1024 * 128;
    const short* vbb = vb + bh * 64 * 1024;
    float* outb = out + bh * 64 * 1024 + mt0 * 128;

    // Phase 0: stage A-side rows [qhi | relhi | qlo | rello] (cols 0/64/128/192)
    {
        int r2 = t >> 2, part = t & 3;
        int dcol = (part == 0) ? 0 : (part == 1) ? 128 : (part == 2) ? 64 : 192;
#pragma unroll
        for (int rr = 0; rr < 2; ++rr) {
            int r = rr * 64 + r2;
            int n = mt0 * 128 + r;
            const short* src = ((part < 2) ? (q2b + (size_t)n * 128)
                                           : (relb + (size_t)n * 128)) + (part & 1) * 64;
            short* dst = qa_s + r * 256 + dcol;
#pragma unroll
            for (int j = 0; j < 8; ++j)
                ((uint4*)dst)[j] = ((const uint4*)src)[j];
        }
    }
    __syncthreads();
    short8 ah[2][4], al[2][4];
#pragma unroll
    for (int rt = 0; rt < 2; ++rt)
#pragma unroll
        for (int kk = 0; kk < 4; ++kk) {
            ah[rt][kk] = *(short8*)&qa_s[(w * 32 + rt * 16 + lm) * 256 + kk * 32 + lq * 8];
            al[rt][kk] = *(short8*)&qa_s[(w * 32 + rt * 16 + lm) * 256 + 128 + kk * 32 + lq * 8];
        }
    f32x4 acco[4][2];
#pragma unroll
    for (int i = 0; i < 4; ++i)
#pragma unroll
        for (int j = 0; j < 2; ++j) acco[i][j] = {0.f, 0.f, 0.f, 0.f};
    float mrun[2][4], lrun[2][4];
#pragma unroll
    for (int i = 0; i < 2; ++i)
#pragma unroll
        for (int j = 0; j < 4; ++j) { mrun[i][j] = -3e38f; lrun[i][j] = 0.f; }

    for (int kt = 0; kt < 16; ++kt) {
        int n0 = kt * 64;
        __syncthreads();  // prior reads of kb_s/v_s (and phase-0 frag reads) done
        {
            // B-side rows: [khi | qhi | klo | qlo] (cols 0/64/128/192)
            int r = t >> 2, part = t & 3;
            int n = n0 + r;
            int dcol = (part == 0) ? 0 : (part == 1) ? 128 : (part == 2) ? 64 : 192;
            const short* src = ((part < 2) ? (k2b + (size_t)n * 128)
                                           : (q2b + (size_t)n * 128)) + (part & 1) * 64;
            short* dst = kb_s + r * 264 + dcol;
#pragma unroll
            for (int j = 0; j < 8; ++j)
                ((uint4*)dst)[j] = ((const uint4*)src)[j];
            int vrow = t >> 3, vcol = (t & 7) * 8;
#pragma unroll
            for (int p = 0; p < 2; ++p)
                *(uint4*)&v_s[(p * 32 + vrow) * 72 + vcol] =
                    *(const uint4*)(vbb + (size_t)(p * 32 + vrow) * 1024 + n0 + vcol);
        }
        __syncthreads();
        f32x4 sac[2][4];
#pragma unroll
        for (int rt = 0; rt < 2; ++rt)
#pragma unroll
            for (int ct = 0; ct < 4; ++ct) sac[rt][ct] = {0.f, 0.f, 0.f, 0.f};
#pragma unroll
        for (int ct = 0; ct < 4; ++ct) {
            short8 bhf[4], blf[4];
#pragma unroll
            for (int kk = 0; kk < 4; ++kk) {
                bhf[kk] = *(short8*)&kb_s[(ct * 16 + lm) * 264 + kk * 32 + lq * 8];
                blf[kk] = *(short8*)&kb_s[(ct * 16 + lm) * 264 + 128 + kk * 32 + lq * 8];
            }
#pragma unroll
            for (int rt = 0; rt < 2; ++rt) {
#pragma unroll
                for (int kk = 0; kk < 4; ++kk)
                    sac[rt][ct] = __builtin_amdgcn_mfma_f32_16x16x32_bf16(ah[rt][kk], bhf[kk], sac[rt][ct], 0, 0, 0);
#pragma unroll
                for (int kk = 0; kk < 4; ++kk)
                    sac[rt][ct] = __builtin_amdgcn_mfma_f32_16x16x32_bf16(al[rt][kk], bhf[kk], sac[rt][ct], 0, 0, 0);
#pragma unroll
                for (int kk = 0; kk < 4; ++kk)
                    sac[rt][ct] = __builtin_amdgcn_mfma_f32_16x16x32_bf16(ah[rt][kk], blf[kk], sac[rt][ct], 0, 0, 0);
            }
        }
        // online softmax (rows are wave-private)
        float pexp[2][4][4], alpha[2][4];
#pragma unroll
        for (int rt = 0; rt < 2; ++rt)
#pragma unroll
            for (int reg = 0; reg < 4; ++reg) {
                float mx = fmaxf(fmaxf(sac[rt][0][reg], sac[rt][1][reg]),
                                 fmaxf(sac[rt][2][reg], sac[rt][3][reg]));
#pragma unroll
                for (int off = 1; off < 16; off <<= 1)
                    mx = fmaxf(mx, __shfl_xor(mx, off, 16));
                float mnew = fmaxf(mrun[rt][reg], mx);
                float al_ = __expf(mrun[rt][reg] - mnew);
                float rsum = 0.f;
#pragma unroll
                for (int ct = 0; ct < 4; ++ct) {
                    float p = __expf(sac[rt][ct][reg] - mnew);
                    pexp[rt][ct][reg] = p;
                    rsum += p;
                }
#pragma unroll
                for (int off = 1; off < 16; off <<= 1)
                    rsum += __shfl_xor(rsum, off, 16);
                lrun[rt][reg] = lrun[rt][reg] * al_ + rsum;
                mrun[rt][reg] = mnew;
                alpha[rt][reg] = al_;
            }
        if (lm == 0)
#pragma unroll
            for (int rt = 0; rt < 2; ++rt)
#pragma unroll
                for (int reg = 0; reg < 4; ++reg)
                    red_s[w * 32 + rt * 16 + lq * 4 + reg] = alpha[rt][reg];
        // wave-private red_s / p_s rows: no barrier needed
#pragma unroll
        for (int cto = 0; cto < 2; ++cto) {
            float al_ = red_s[w * 32 + cto * 16 + lm];
#pragma unroll
            for (int dt = 0; dt < 4; ++dt) {
                acco[dt][cto][0] *= al_; acco[dt][cto][1] *= al_;
                acco[dt][cto][2] *= al_; acco[dt][cto][3] *= al_;
            }
        }
#pragma unroll
        for (int rt = 0; rt < 2; ++rt)
#pragma unroll
            for (int ct = 0; ct < 4; ++ct)
#pragma unroll
                for (int reg = 0; reg < 4; ++reg)
                    p_s[(w * 32 + rt * 16 + lq * 4 + reg) * 72 + ct * 16 + lm] =
                        f2bf(pexp[rt][ct][reg]);
        // PV: out^T[d][m] += v * P^T
#pragma unroll
        for (int cto = 0; cto < 2; ++cto) {
            short8 pfr[2];
#pragma unroll
            for (int kk = 0; kk < 2; ++kk)
                pfr[kk] = *(short8*)&p_s[(w * 32 + cto * 16 + lm) * 72 + kk * 32 + lq * 8];
#pragma unroll
            for (int dt = 0; dt < 4; ++dt) {
                short8 vf0 = *(short8*)&v_s[(dt * 16 + lm) * 72 + lq * 8];
                short8 vf1 = *(short8*)&v_s[(dt * 16 + lm) * 72 + 32 + lq * 8];
                acco[dt][cto] = __builtin_amdgcn_mfma_f32_16x16x32_bf16(vf0, pfr[0], acco[dt][cto], 0, 0, 0);
                acco[dt][cto] = __builtin_amdgcn_mfma_f32_16x16x32_bf16(vf1, pfr[1], acco[dt][cto], 0, 0, 0);
            }
        }
    }
    if (lm == 0)
#pragma unroll
        for (int rt = 0; rt < 2; ++rt)
#pragma unroll
            for (int reg = 0; reg < 4; ++reg)
                red_s[w * 32 + rt * 16 + lq * 4 + reg] = 1.f / lrun[rt][reg];
#pragma unroll
    for (int cto = 0; cto < 2; ++cto) {
        float li = red_s[w * 32 + cto * 16 + lm];
#pragma unroll
        for (int dt = 0; dt < 4; ++dt)
#pragma unroll
            for (int reg = 0; reg < 4; ++reg) {
                int d = dt * 16 + lq * 4 + reg;
                outb[(size_t)d * 1024 + w * 32 + cto * 16 + lm] = acco[dt][cto][reg] * li;
            }
    }
}

extern "C" void kernel_launch(void* const* d_in, const int* in_sizes, int n_in,
                              void* d_out, int out_size, void* d_ws, size_t ws_size,
                              hipStream_t stream) {
    const float* x     = (const float*)d_in[0];
    const float* Wq    = (const float*)d_in[1];
    const float* bq    = (const float*)d_in[2];
    const float* Wk    = (const float*)d_in[3];
    const float* bk    = (const float*)d_in[4];
    const float* Wv    = (const float*)d_in[5];
    const float* bv    = (const float*)d_in[6];
    const float* rel_h = (const float*)d_in[7];
    const float* rel_w = (const float*)d_in[8];
    char* ws = (char*)d_ws;
    // Region A (dead after k_proj): A2 + bias2 + xT2 = 29,890,560 B
    short* A2    = (short*)(ws);                  //  4,718,592 B
    float* bias2 = (float*)(ws + 4718592);        //      6,144 B
    short* xT2   = (short*)(ws + 4724736);        // 25,165,824 B -> end 29,890,560
    float* qkv   = (float*)(ws + 29890560);       // 50,331,648 B -> end 80,222,208
    short* vb    = (short*)(ws + 80222208);       //  8,388,608 B -> end 88,610,816
    short* k2    = (short*)(ws + 88610816);       // 16,777,216 B -> end 105,388,032
    // Reuse region A after k_proj (stream-ordered):
    short* q2    = (short*)(ws);                  // 16,777,216 B (over A2/xT2)
    short* rel2  = (short*)(ws + 16777216);       //  2,097,152 B (within region A)
    float* out = (float*)d_out;

    hipLaunchKernelGGL(k_pack_w,   dim3(384),      dim3(256), 0, stream, Wq, Wk, Wv, bq, bk, bv, A2, bias2);
    hipLaunchKernelGGL(k_prep_x,   dim3(16, 8, 8), dim3(256), 0, stream, x, xT2);
    hipLaunchKernelGGL(k_proj,     dim3(8, 12, 8), dim3(256), 0, stream, A2, xT2, bias2, qkv);
    hipLaunchKernelGGL(k_vb,       dim3(2048),     dim3(256), 0, stream, qkv, vb);
    hipLaunchKernelGGL(k_prep_rel, dim3(256),      dim3(256), 0, stream, rel_h, rel_w, rel2);
    hipLaunchKernelGGL(k_prep_qk,  dim3(16, 8, 8), dim3(256), 0, stream, qkv, q2, k2);
    hipLaunchKernelGGL(k_attn,     dim3(8, 8, 8),  dim3(256), 0, stream, q2, k2, rel2, vb, out);
}

// Round 4
// 233.295 us; speedup vs baseline: 1.2850x; 1.2850x over previous
//
#include <hip/hip_runtime.h>

typedef short short8 __attribute__((ext_vector_type(8)));
typedef _Float16 half8 __attribute__((ext_vector_type(8)));
typedef float f32x4 __attribute__((ext_vector_type(4)));

// bf16 bit helpers (RNE)
__device__ __forceinline__ short f2bf(float f) {
    union { float f; unsigned u; } c; c.f = f;
    unsigned r = c.u + 0x7fffu + ((c.u >> 16) & 1u);
    return (short)(r >> 16);
}
__device__ __forceinline__ float bf2f(short s) {
    union { unsigned u; float f; } c; c.u = ((unsigned)(unsigned short)s) << 16;
    return c.f;
}

__device__ __forceinline__ void glds16(const void* g, void* l) {
    __builtin_amdgcn_global_load_lds(
        (const __attribute__((address_space(1))) unsigned int*)g,
        (__attribute__((address_space(3))) unsigned int*)l, 16, 0, 0);
}

// ---------------------------------------------------------------------------
// Sizes: B=8, C=512, H=8, D=64, N=1024, proj M=K=1536 (3C rows / split-K cols)
// ---------------------------------------------------------------------------

// Pack Wq/Wk/Wv into A2[1536][1536] = [Whi | Whi | Wlo] rows, plus bias2[1536].
__global__ void k_pack_w(const float* __restrict__ Wq, const float* __restrict__ Wk,
                         const float* __restrict__ Wv, const float* __restrict__ bq,
                         const float* __restrict__ bk, const float* __restrict__ bv,
                         short* __restrict__ A2, float* __restrict__ bias2) {
    int t = blockIdx.x * 256 + threadIdx.x;      // 98304 threads
    int m = t >> 6;
    int c8 = (t & 63) << 3;
    const float* src = (m < 512) ? (Wq + m * 512)
                     : (m < 1024 ? (Wk + (m - 512) * 512) : (Wv + (m - 1024) * 512));
    float4 v0 = *(const float4*)(src + c8);
    float4 v1 = *(const float4*)(src + c8 + 4);
    float f[8] = {v0.x, v0.y, v0.z, v0.w, v1.x, v1.y, v1.z, v1.w};
    short8 hi, lo;
#pragma unroll
    for (int j = 0; j < 8; ++j) {
        short h = f2bf(f[j]);
        hi[j] = h;
        lo[j] = f2bf(f[j] - bf2f(h));
    }
    short* rowp = A2 + (size_t)m * 1536;
    *(short8*)(rowp + c8)        = hi;
    *(short8*)(rowp + 512 + c8)  = hi;
    *(short8*)(rowp + 1024 + c8) = lo;
    if (t < 1536)
        bias2[t] = (t < 512) ? bq[t] : (t < 1024 ? bk[t - 512] : bv[t - 1024]);
}

// Transpose x[b][c][n] -> xT2[b][n][1536] = [xhi | xlo | xhi] (k-contiguous rows)
__global__ void k_prep_x(const float* __restrict__ x, short* __restrict__ xT2) {
    __shared__ float xs[64][65];
    int nt = blockIdx.x * 64, ct = blockIdx.y * 64, b = blockIdx.z;
    int t = threadIdx.x;
    const float* xb = x + ((size_t)b * 512 + ct) * 1024 + nt;
#pragma unroll
    for (int p = 0; p < 4; ++p) {
        int c = p * 16 + (t >> 4), n4 = (t & 15) * 4;
        float4 v = *(const float4*)(xb + (size_t)c * 1024 + n4);
        xs[c][n4] = v.x; xs[c][n4 + 1] = v.y; xs[c][n4 + 2] = v.z; xs[c][n4 + 3] = v.w;
    }
    __syncthreads();
    int nl = t >> 2, part = t & 3;
    short* rowp = xT2 + ((size_t)b * 1024 + nt + nl) * 1536;
#pragma unroll
    for (int g = 0; g < 2; ++g) {
        short8 hi, lo;
#pragma unroll
        for (int j = 0; j < 8; ++j) {
            float f = xs[part * 16 + g * 8 + j][nl];
            short h = f2bf(f);
            hi[j] = h; lo[j] = f2bf(f - bf2f(h));
        }
        int c = ct + part * 16 + g * 8;
        *(short8*)(rowp + c)        = hi;
        *(short8*)(rowp + 512 + c)  = lo;
        *(short8*)(rowp + 1024 + c) = hi;
    }
}

// Split-bf16 GEMM via global_load_lds(16B) + XOR-swizzled unpadded LDS tiles.
__global__ __launch_bounds__(256) void k_proj(const short* __restrict__ A2,
                                              const short* __restrict__ xT2,
                                              const float* __restrict__ bias2,
                                              float* __restrict__ qkv) {
    __shared__ __align__(16) short As[4096];   // [128 rows][32 shorts], XOR-swizzled
    __shared__ __align__(16) short Bs[4096];
    int t = threadIdx.x;
    int lane = t & 63, w = t >> 6;
    int lm = lane & 15, lq = lane >> 4;
    int wr = (w >> 1) * 64, wc = (w & 1) * 64;
    int mb = blockIdx.y * 128, nb = blockIdx.x * 128, b = blockIdx.z;
    int rl = lane >> 2;                                   // row within 16-row group
    int csw = ((lane & 3) ^ ((lane >> 3) & 3)) * 8;       // swizzled col (shorts)
    const short* Ag0 = A2 + (size_t)(mb + w * 32 + rl) * 1536 + csw;
    const short* Ag1 = Ag0 + 16 * 1536;
    const short* Bg0 = xT2 + ((size_t)b * 1024 + nb + w * 32 + rl) * 1536 + csw;
    const short* Bg1 = Bg0 + 16 * 1536;
    short* Adst0 = &As[(w * 32) * 32];
    short* Adst1 = &As[(w * 32 + 16) * 32];
    short* Bdst0 = &Bs[(w * 32) * 32];
    short* Bdst1 = &Bs[(w * 32 + 16) * 32];
    f32x4 acc[4][4];
#pragma unroll
    for (int i = 0; i < 4; ++i)
#pragma unroll
        for (int j = 0; j < 4; ++j) acc[i][j] = {0.f, 0.f, 0.f, 0.f};
    int fsw = (lq ^ ((lm >> 1) & 3)) * 8;                 // fragment-read swizzle
    for (int k0 = 0; k0 < 1536; k0 += 32) {
        glds16(Ag0 + k0, Adst0);
        glds16(Ag1 + k0, Adst1);
        glds16(Bg0 + k0, Bdst0);
        glds16(Bg1 + k0, Bdst1);
        __syncthreads();
        short8 af[4], bfr[4];
#pragma unroll
        for (int mt = 0; mt < 4; ++mt)
            af[mt] = *(short8*)&As[(wr + mt * 16 + lm) * 32 + fsw];
#pragma unroll
        for (int nt = 0; nt < 4; ++nt)
            bfr[nt] = *(short8*)&Bs[(wc + nt * 16 + lm) * 32 + fsw];
#pragma unroll
        for (int mt = 0; mt < 4; ++mt)
#pragma unroll
            for (int nt = 0; nt < 4; ++nt)
                acc[mt][nt] = __builtin_amdgcn_mfma_f32_16x16x32_bf16(af[mt], bfr[nt], acc[mt][nt], 0, 0, 0);
        __syncthreads();
    }
#pragma unroll
    for (int mt = 0; mt < 4; ++mt)
#pragma unroll
        for (int reg = 0; reg < 4; ++reg) {
            int row = mb + wr + mt * 16 + lq * 4 + reg;
            float bias = bias2[row];
#pragma unroll
            for (int nt = 0; nt < 4; ++nt) {
                int col = nb + wc + nt * 16 + lm;
                qkv[((size_t)b * 1536 + row) * 1024 + col] = acc[mt][nt][reg] + bias;
            }
        }
}

// v rows -> fp16 (native [b][h][d][n] layout)
__global__ void k_vb(const float* __restrict__ qkv, _Float16* __restrict__ vb) {
    size_t i8 = ((size_t)blockIdx.x * 256 + threadIdx.x) * 8;
    size_t b = i8 >> 19;
    size_t rem = i8 & 524287;
    const float* src = qkv + b * 1572864 + 1048576 + rem;
    float4 v0 = *(const float4*)src;
    float4 v1 = *(const float4*)(src + 4);
    half8 o;
    o[0] = (_Float16)v0.x; o[1] = (_Float16)v0.y; o[2] = (_Float16)v0.z; o[3] = (_Float16)v0.w;
    o[4] = (_Float16)v1.x; o[5] = (_Float16)v1.y; o[6] = (_Float16)v1.z; o[7] = (_Float16)v1.w;
    *(half8*)(vb + i8) = o;
}

// rel2[h][n][64] fp16
__global__ void k_prep_rel(const float* __restrict__ rel_h, const float* __restrict__ rel_w,
                           _Float16* __restrict__ rel2) {
    int tid = blockIdx.x * 256 + threadIdx.x;   // 65536
    int h = tid >> 13;
    int rem = tid & 8191;
    int n = rem >> 3;
    int g = rem & 7;
    int hh = n & 31, ww = n >> 5;
    half8 o;
#pragma unroll
    for (int j = 0; j < 8; ++j) {
        int d = g * 8 + j;
        o[j] = (_Float16)(rel_h[(h * 64 + d) * 32 + hh] + rel_w[(h * 64 + d) * 32 + ww]);
    }
    *(half8*)(rel2 + ((size_t)h * 1024 + n) * 64 + g * 8) = o;
}

// Transpose q,k head-tiles to fp16 rows: q2[bh][n][64], k2[bh][n][64]
__global__ void k_prep_qk(const float* __restrict__ qkv, _Float16* __restrict__ q2,
                          _Float16* __restrict__ k2) {
    __shared__ float qs[64][65];
    __shared__ float ks[64][65];
    int nt = blockIdx.x * 64, h = blockIdx.y, b = blockIdx.z;
    int t = threadIdx.x;
    const float* qg = qkv + ((size_t)b * 1536 + h * 64) * 1024 + nt;
    const float* kg = qkv + ((size_t)b * 1536 + 512 + h * 64) * 1024 + nt;
#pragma unroll
    for (int p = 0; p < 4; ++p) {
        int d = p * 16 + (t >> 4), n4 = (t & 15) * 4;
        float4 v = *(const float4*)(qg + (size_t)d * 1024 + n4);
        qs[d][n4] = v.x; qs[d][n4 + 1] = v.y; qs[d][n4 + 2] = v.z; qs[d][n4 + 3] = v.w;
        float4 u = *(const float4*)(kg + (size_t)d * 1024 + n4);
        ks[d][n4] = u.x; ks[d][n4 + 1] = u.y; ks[d][n4 + 2] = u.z; ks[d][n4 + 3] = u.w;
    }
    __syncthreads();
    int nl = t >> 2, part = t & 3;
    int n = nt + nl;
    size_t bh = (size_t)b * 8 + h;
    _Float16* qrow = q2 + (bh * 1024 + n) * 64;
    _Float16* krow = k2 + (bh * 1024 + n) * 64;
#pragma unroll
    for (int g = 0; g < 2; ++g) {
        int d0 = part * 16 + g * 8;
        half8 hq, hk;
#pragma unroll
        for (int j = 0; j < 8; ++j) {
            hq[j] = (_Float16)qs[d0 + j][nl];
            hk[j] = (_Float16)ks[d0 + j][nl];
        }
        *(half8*)(qrow + d0) = hq;
        *(half8*)(krow + d0) = hk;
    }
}

// Flash attention, fp16 single-product. One block per (b,h,64-query tile).
// A-rows [q|rel] (aug dim 128), B-rows [k|q]; S[m][n]=q_m·k_n + rel_m·q_n.
// Online softmax; P relayout via wave-private LDS rows; out written [d][m].
__global__ __launch_bounds__(256) void k_attn(const _Float16* __restrict__ q2,
                                              const _Float16* __restrict__ k2,
                                              const _Float16* __restrict__ rel2,
                                              const _Float16* __restrict__ vb,
                                              float* __restrict__ out) {
    __shared__ __align__(16) char pool[36352];
    _Float16* kb_s = (_Float16*)pool;            // [64][136] = 17408 B (phase-0: qa rows)
    _Float16* v_s  = (_Float16*)(pool + 17408);  // [64][72]  =  9216 B
    _Float16* p_s  = (_Float16*)(pool + 26624);  // [64][72]  =  9216 B
    float* red_s   = (float*)(pool + 35840);     // [64]      =   256 B
    int t = threadIdx.x;
    int lane = t & 63, w = t >> 6;
    int lm = lane & 15, lq = lane >> 4;
    int mt0 = blockIdx.x, h = blockIdx.y, b = blockIdx.z;
    size_t bh = (size_t)b * 8 + h;
    const _Float16* q2b = q2 + bh * 1024 * 64;
    const _Float16* k2b = k2 + bh * 1024 * 64;
    const _Float16* relb = rel2 + (size_t)h * 1024 * 64;
    const _Float16* vbb = vb + bh * 64 * 1024;
    float* outb = out + bh * 64 * 1024 + mt0 * 64;
    // Phase 0: stage A-side rows [q | rel] for m = mt0*64 .. +63 (aliases kb_s)
    // Each part covers 32 halfs = 64 B = 4 x uint4.
    {
        int r = t >> 2, part = t & 3;
        int n = mt0 * 64 + r;
        const _Float16* src = (part < 2) ? (q2b + (size_t)n * 64 + part * 32)
                                         : (relb + (size_t)n * 64 + (part - 2) * 32);
        _Float16* dst = kb_s + r * 136 + part * 32;
        ((uint4*)dst)[0] = ((const uint4*)src)[0];
        ((uint4*)dst)[1] = ((const uint4*)src)[1];
        ((uint4*)dst)[2] = ((const uint4*)src)[2];
        ((uint4*)dst)[3] = ((const uint4*)src)[3];
    }
    __syncthreads();
    half8 ah[4];
#pragma unroll
    for (int kk = 0; kk < 4; ++kk)
        ah[kk] = *(half8*)&kb_s[(w * 16 + lm) * 136 + kk * 32 + lq * 8];
    f32x4 acco[4];
#pragma unroll
    for (int i = 0; i < 4; ++i) acco[i] = {0.f, 0.f, 0.f, 0.f};
    float mrun[4], lrun[4];
#pragma unroll
    for (int j = 0; j < 4; ++j) { mrun[j] = -3e38f; lrun[j] = 0.f; }

    for (int kt = 0; kt < 16; ++kt) {
        int n0 = kt * 64;
        __syncthreads();  // prior QK/PV reads of kb_s/v_s (and phase-0 A reads) done
        {
            int r = t >> 2, part = t & 3;
            int n = n0 + r;
            const _Float16* src = (part < 2) ? (k2b + (size_t)n * 64 + part * 32)
                                             : (q2b + (size_t)n * 64 + (part - 2) * 32);
            _Float16* dst = kb_s + r * 136 + part * 32;
            ((uint4*)dst)[0] = ((const uint4*)src)[0];
            ((uint4*)dst)[1] = ((const uint4*)src)[1];
            ((uint4*)dst)[2] = ((const uint4*)src)[2];
            ((uint4*)dst)[3] = ((const uint4*)src)[3];
            int vc = (t & 3) * 16;
            const _Float16* vsrc = vbb + (size_t)r * 1024 + n0 + vc;
            _Float16* vdst = v_s + r * 72 + vc;
            ((uint4*)vdst)[0] = ((const uint4*)vsrc)[0];
            ((uint4*)vdst)[1] = ((const uint4*)vsrc)[1];
        }
        __syncthreads();
        f32x4 sac[4];
#pragma unroll
        for (int ct = 0; ct < 4; ++ct) sac[ct] = {0.f, 0.f, 0.f, 0.f};
#pragma unroll
        for (int ct = 0; ct < 4; ++ct) {
            half8 bf[4];
#pragma unroll
            for (int kk = 0; kk < 4; ++kk)
                bf[kk] = *(half8*)&kb_s[(ct * 16 + lm) * 136 + kk * 32 + lq * 8];
#pragma unroll
            for (int kk = 0; kk < 4; ++kk)
                sac[ct] = __builtin_amdgcn_mfma_f32_16x16x32_f16(ah[kk], bf[kk], sac[ct], 0, 0, 0);
        }
        // online softmax (rows m = w*16 + lq*4 + reg, cols n = ct*16 + lm)
        float pexp[4][4], alpha[4];
#pragma unroll
        for (int reg = 0; reg < 4; ++reg) {
            float mx = fmaxf(fmaxf(sac[0][reg], sac[1][reg]),
                             fmaxf(sac[2][reg], sac[3][reg]));
#pragma unroll
            for (int off = 1; off < 16; off <<= 1)
                mx = fmaxf(mx, __shfl_xor(mx, off, 16));
            float mnew = fmaxf(mrun[reg], mx);
            float al_ = __expf(mrun[reg] - mnew);
            float rsum = 0.f;
#pragma unroll
            for (int ct = 0; ct < 4; ++ct) {
                float p = __expf(sac[ct][reg] - mnew);
                pexp[ct][reg] = p;
                rsum += p;
            }
#pragma unroll
            for (int off = 1; off < 16; off <<= 1)
                rsum += __shfl_xor(rsum, off, 16);
            lrun[reg] = lrun[reg] * al_ + rsum;
            mrun[reg] = mnew;
            alpha[reg] = al_;
        }
        if (lm == 0)
#pragma unroll
            for (int reg = 0; reg < 4; ++reg)
                red_s[w * 16 + lq * 4 + reg] = alpha[reg];
        // wave-private red_s / p_s rows: no barrier needed
        {
            float al_ = red_s[w * 16 + lm];
#pragma unroll
            for (int dt = 0; dt < 4; ++dt) {
                acco[dt][0] *= al_; acco[dt][1] *= al_;
                acco[dt][2] *= al_; acco[dt][3] *= al_;
            }
        }
#pragma unroll
        for (int ct = 0; ct < 4; ++ct)
#pragma unroll
            for (int reg = 0; reg < 4; ++reg)
                p_s[(w * 16 + lq * 4 + reg) * 72 + ct * 16 + lm] = (_Float16)pexp[ct][reg];
        // PV: out^T[d][m] += v * P^T  (m-cols = this wave's own 16 rows)
        half8 pfr[2];
#pragma unroll
        for (int kk = 0; kk < 2; ++kk)
            pfr[kk] = *(half8*)&p_s[(w * 16 + lm) * 72 + kk * 32 + lq * 8];
#pragma unroll
        for (int dt = 0; dt < 4; ++dt) {
            half8 vf0 = *(half8*)&v_s[(dt * 16 + lm) * 72 + lq * 8];
            half8 vf1 = *(half8*)&v_s[(dt * 16 + lm) * 72 + 32 + lq * 8];
            acco[dt] = __builtin_amdgcn_mfma_f32_16x16x32_f16(vf0, pfr[0], acco[dt], 0, 0, 0);
            acco[dt] = __builtin_amdgcn_mfma_f32_16x16x32_f16(vf1, pfr[1], acco[dt], 0, 0, 0);
        }
    }
    if (lm == 0)
#pragma unroll
        for (int reg = 0; reg < 4; ++reg)
            red_s[w * 16 + lq * 4 + reg] = 1.f / lrun[reg];
    {
        float li = red_s[w * 16 + lm];
#pragma unroll
        for (int dt = 0; dt < 4; ++dt)
#pragma unroll
            for (int reg = 0; reg < 4; ++reg) {
                int d = dt * 16 + lq * 4 + reg;
                outb[(size_t)d * 1024 + w * 16 + lm] = acco[dt][reg] * li;
            }
    }
}

extern "C" void kernel_launch(void* const* d_in, const int* in_sizes, int n_in,
                              void* d_out, int out_size, void* d_ws, size_t ws_size,
                              hipStream_t stream) {
    const float* x     = (const float*)d_in[0];
    const float* Wq    = (const float*)d_in[1];
    const float* bq    = (const float*)d_in[2];
    const float* Wk    = (const float*)d_in[3];
    const float* bk    = (const float*)d_in[4];
    const float* Wv    = (const float*)d_in[5];
    const float* bv    = (const float*)d_in[6];
    const float* rel_h = (const float*)d_in[7];
    const float* rel_w = (const float*)d_in[8];
    char* ws = (char*)d_ws;
    // Region A (dead after k_proj): A2 + bias2 + xT2 = 29,890,560 B
    short* A2      = (short*)(ws);                  //  4,718,592 B
    float* bias2   = (float*)(ws + 4718592);        //      6,144 B
    short* xT2     = (short*)(ws + 4724736);        // 25,165,824 B -> end 29,890,560
    float* qkv     = (float*)(ws + 29890560);       // 50,331,648 B -> end 80,222,208
    _Float16* vb   = (_Float16*)(ws + 80222208);    //  8,388,608 B -> end 88,610,816
    _Float16* k2   = (_Float16*)(ws + 88610816);    //  8,388,608 B -> end 96,999,424
    // Reuse region A after k_proj (stream-ordered):
    _Float16* q2   = (_Float16*)(ws);               //  8,388,608 B (over A2/xT2)
    _Float16* rel2 = (_Float16*)(ws + 8388608);     //  1,048,576 B (within region A)
    float* out = (float*)d_out;

    hipLaunchKernelGGL(k_pack_w,   dim3(384),      dim3(256), 0, stream, Wq, Wk, Wv, bq, bk, bv, A2, bias2);
    hipLaunchKernelGGL(k_prep_x,   dim3(16, 8, 8), dim3(256), 0, stream, x, xT2);
    hipLaunchKernelGGL(k_proj,     dim3(8, 12, 8), dim3(256), 0, stream, A2, xT2, bias2, qkv);
    hipLaunchKernelGGL(k_vb,       dim3(2048),     dim3(256), 0, stream, qkv, vb);
    hipLaunchKernelGGL(k_prep_rel, dim3(256),      dim3(256), 0, stream, rel_h, rel_w, rel2);
    hipLaunchKernelGGL(k_prep_qk,  dim3(16, 8, 8), dim3(256), 0, stream, qkv, q2, k2);
    hipLaunchKernelGGL(k_attn,     dim3(16, 8, 8), dim3(256), 0, stream, q2, k2, rel2, vb, out);
}

// Round 5
// 220.255 us; speedup vs baseline: 1.3610x; 1.0592x over previous
//
#include <hip/hip_runtime.h>

typedef short short8 __attribute__((ext_vector_type(8)));
typedef _Float16 half8 __attribute__((ext_vector_type(8)));
typedef _Float16 half4 __attribute__((ext_vector_type(4)));
typedef float f32x4 __attribute__((ext_vector_type(4)));

// bf16 bit helpers (RNE)
__device__ __forceinline__ short f2bf(float f) {
    union { float f; unsigned u; } c; c.f = f;
    unsigned r = c.u + 0x7fffu + ((c.u >> 16) & 1u);
    return (short)(r >> 16);
}
__device__ __forceinline__ float bf2f(short s) {
    union { unsigned u; float f; } c; c.u = ((unsigned)(unsigned short)s) << 16;
    return c.f;
}

__device__ __forceinline__ void glds16(const void* g, void* l) {
    __builtin_amdgcn_global_load_lds(
        (const __attribute__((address_space(1))) unsigned int*)g,
        (__attribute__((address_space(3))) unsigned int*)l, 16, 0, 0);
}

// ---------------------------------------------------------------------------
// Sizes: B=8, C=512, H=8, D=64, N=1024, proj M=K=1536 (3C rows / split-K cols)
// ---------------------------------------------------------------------------

// Pack Wq/Wk/Wv into A2[1536][1536] = [Whi | Whi | Wlo] rows, plus bias2[1536].
__global__ void k_pack_w(const float* __restrict__ Wq, const float* __restrict__ Wk,
                         const float* __restrict__ Wv, const float* __restrict__ bq,
                         const float* __restrict__ bk, const float* __restrict__ bv,
                         short* __restrict__ A2, float* __restrict__ bias2) {
    int t = blockIdx.x * 256 + threadIdx.x;      // 98304 threads
    int m = t >> 6;
    int c8 = (t & 63) << 3;
    const float* src = (m < 512) ? (Wq + m * 512)
                     : (m < 1024 ? (Wk + (m - 512) * 512) : (Wv + (m - 1024) * 512));
    float4 v0 = *(const float4*)(src + c8);
    float4 v1 = *(const float4*)(src + c8 + 4);
    float f[8] = {v0.x, v0.y, v0.z, v0.w, v1.x, v1.y, v1.z, v1.w};
    short8 hi, lo;
#pragma unroll
    for (int j = 0; j < 8; ++j) {
        short h = f2bf(f[j]);
        hi[j] = h;
        lo[j] = f2bf(f[j] - bf2f(h));
    }
    short* rowp = A2 + (size_t)m * 1536;
    *(short8*)(rowp + c8)        = hi;
    *(short8*)(rowp + 512 + c8)  = hi;
    *(short8*)(rowp + 1024 + c8) = lo;
    if (t < 1536)
        bias2[t] = (t < 512) ? bq[t] : (t < 1024 ? bk[t - 512] : bv[t - 1024]);
}

// Transpose x[b][c][n] -> xT2[b][n][1536] = [xhi | xlo | xhi] (k-contiguous rows)
__global__ void k_prep_x(const float* __restrict__ x, short* __restrict__ xT2) {
    __shared__ float xs[64][65];
    int nt = blockIdx.x * 64, ct = blockIdx.y * 64, b = blockIdx.z;
    int t = threadIdx.x;
    const float* xb = x + ((size_t)b * 512 + ct) * 1024 + nt;
#pragma unroll
    for (int p = 0; p < 4; ++p) {
        int c = p * 16 + (t >> 4), n4 = (t & 15) * 4;
        float4 v = *(const float4*)(xb + (size_t)c * 1024 + n4);
        xs[c][n4] = v.x; xs[c][n4 + 1] = v.y; xs[c][n4 + 2] = v.z; xs[c][n4 + 3] = v.w;
    }
    __syncthreads();
    int nl = t >> 2, part = t & 3;
    short* rowp = xT2 + ((size_t)b * 1024 + nt + nl) * 1536;
#pragma unroll
    for (int g = 0; g < 2; ++g) {
        short8 hi, lo;
#pragma unroll
        for (int j = 0; j < 8; ++j) {
            float f = xs[part * 16 + g * 8 + j][nl];
            short h = f2bf(f);
            hi[j] = h; lo[j] = f2bf(f - bf2f(h));
        }
        int c = ct + part * 16 + g * 8;
        *(short8*)(rowp + c)        = hi;
        *(short8*)(rowp + 512 + c)  = lo;
        *(short8*)(rowp + 1024 + c) = hi;
    }
}

// rel2[h][n][64] fp16
__global__ void k_prep_rel(const float* __restrict__ rel_h, const float* __restrict__ rel_w,
                           _Float16* __restrict__ rel2) {
    int tid = blockIdx.x * 256 + threadIdx.x;   // 65536
    int h = tid >> 13;
    int rem = tid & 8191;
    int n = rem >> 3;
    int g = rem & 7;
    int hh = n & 31, ww = n >> 5;
    half8 o;
#pragma unroll
    for (int j = 0; j < 8; ++j) {
        int d = g * 8 + j;
        o[j] = (_Float16)(rel_h[(h * 64 + d) * 32 + hh] + rel_w[(h * 64 + d) * 32 + ww]);
    }
    *(half8*)(rel2 + ((size_t)h * 1024 + n) * 64 + g * 8) = o;
}

// Split-bf16 GEMM via global_load_lds(16B) + XOR-swizzled unpadded LDS tiles.
// Fused epilogue: writes q2/k2 (fp16, [bh][n][d] transposed) and vb (fp16 [bh][d][n]).
__global__ __launch_bounds__(256) void k_proj(const short* __restrict__ A2,
                                              const short* __restrict__ xT2,
                                              const float* __restrict__ bias2,
                                              _Float16* __restrict__ q2,
                                              _Float16* __restrict__ k2,
                                              _Float16* __restrict__ vb) {
    __shared__ __align__(16) short As[4096];   // [128 rows][32 shorts], XOR-swizzled
    __shared__ __align__(16) short Bs[4096];
    int t = threadIdx.x;
    int lane = t & 63, w = t >> 6;
    int lm = lane & 15, lq = lane >> 4;
    int wr = (w >> 1) * 64, wc = (w & 1) * 64;
    int mb = blockIdx.y * 128, nb = blockIdx.x * 128, b = blockIdx.z;
    int rl = lane >> 2;                                   // row within 16-row group
    int csw = ((lane & 3) ^ ((lane >> 3) & 3)) * 8;       // swizzled col (shorts)
    const short* Ag0 = A2 + (size_t)(mb + w * 32 + rl) * 1536 + csw;
    const short* Ag1 = Ag0 + 16 * 1536;
    const short* Bg0 = xT2 + ((size_t)b * 1024 + nb + w * 32 + rl) * 1536 + csw;
    const short* Bg1 = Bg0 + 16 * 1536;
    short* Adst0 = &As[(w * 32) * 32];
    short* Adst1 = &As[(w * 32 + 16) * 32];
    short* Bdst0 = &Bs[(w * 32) * 32];
    short* Bdst1 = &Bs[(w * 32 + 16) * 32];
    f32x4 acc[4][4];
#pragma unroll
    for (int i = 0; i < 4; ++i)
#pragma unroll
        for (int j = 0; j < 4; ++j) acc[i][j] = {0.f, 0.f, 0.f, 0.f};
    int fsw = (lq ^ ((lm >> 1) & 3)) * 8;                 // fragment-read swizzle
    for (int k0 = 0; k0 < 1536; k0 += 32) {
        glds16(Ag0 + k0, Adst0);
        glds16(Ag1 + k0, Adst1);
        glds16(Bg0 + k0, Bdst0);
        glds16(Bg1 + k0, Bdst1);
        __syncthreads();
        short8 af[4], bfr[4];
#pragma unroll
        for (int mt = 0; mt < 4; ++mt)
            af[mt] = *(short8*)&As[(wr + mt * 16 + lm) * 32 + fsw];
#pragma unroll
        for (int nt = 0; nt < 4; ++nt)
            bfr[nt] = *(short8*)&Bs[(wc + nt * 16 + lm) * 32 + fsw];
#pragma unroll
        for (int mt = 0; mt < 4; ++mt)
#pragma unroll
            for (int nt = 0; nt < 4; ++nt)
                acc[mt][nt] = __builtin_amdgcn_mfma_f32_16x16x32_bf16(af[mt], bfr[nt], acc[mt][nt], 0, 0, 0);
        __syncthreads();
    }
    // Epilogue: section 0=q (rows 0-511), 1=k, 2=v; head-aligned since (mb+wr)%64==0
    int sect = mb >> 9;
    int hloc = ((mb & 511) + wr) >> 6;
    size_t bh = (size_t)b * 8 + hloc;
    if (sect < 2) {
        _Float16* dst = (sect == 0 ? q2 : k2) + bh * 1024 * 64;
#pragma unroll
        for (int mt = 0; mt < 4; ++mt) {
            int d0 = mt * 16 + lq * 4;
            float bi0 = bias2[mb + wr + d0];
            float bi1 = bias2[mb + wr + d0 + 1];
            float bi2 = bias2[mb + wr + d0 + 2];
            float bi3 = bias2[mb + wr + d0 + 3];
#pragma unroll
            for (int nt = 0; nt < 4; ++nt) {
                int n = nb + wc + nt * 16 + lm;
                half4 o;
                o[0] = (_Float16)(acc[mt][nt][0] + bi0);
                o[1] = (_Float16)(acc[mt][nt][1] + bi1);
                o[2] = (_Float16)(acc[mt][nt][2] + bi2);
                o[3] = (_Float16)(acc[mt][nt][3] + bi3);
                *(half4*)(dst + (size_t)n * 64 + d0) = o;
            }
        }
    } else {
        _Float16* dst = vb + bh * 64 * 1024;
#pragma unroll
        for (int mt = 0; mt < 4; ++mt)
#pragma unroll
            for (int reg = 0; reg < 4; ++reg) {
                int d = mt * 16 + lq * 4 + reg;
                float bi = bias2[mb + wr + d];
#pragma unroll
                for (int nt = 0; nt < 4; ++nt) {
                    int n = nb + wc + nt * 16 + lm;
                    dst[(size_t)d * 1024 + n] = (_Float16)(acc[mt][nt][reg] + bi);
                }
            }
    }
}

// Flash attention, fp16, S^T orientation: A=k-rows, B=q-rows so Sᵀ[n][m] has
// m on lanes (col=lm) and n on regs — softmax reduction is in-lane + 2 shuffles,
// alpha/1/l are per-lane scalars, P store is 4×b64. One block per (b,h,64 queries).
__global__ __launch_bounds__(256) void k_attn(const _Float16* __restrict__ q2,
                                              const _Float16* __restrict__ k2,
                                              const _Float16* __restrict__ rel2,
                                              const _Float16* __restrict__ vb,
                                              float* __restrict__ out) {
    __shared__ __align__(16) char pool[35840];
    _Float16* kb_s = (_Float16*)pool;            // [64][136] = 17408 B (phase-0: qa rows)
    _Float16* v_s  = (_Float16*)(pool + 17408);  // [64][72]  =  9216 B
    _Float16* p_s  = (_Float16*)(pool + 26624);  // [64 m][72 n] = 9216 B (wave-private rows)
    int t = threadIdx.x;
    int lane = t & 63, w = t >> 6;
    int lm = lane & 15, lq = lane >> 4;
    int mt0 = blockIdx.x, h = blockIdx.y, b = blockIdx.z;
    size_t bh = (size_t)b * 8 + h;
    const _Float16* q2b = q2 + bh * 1024 * 64;
    const _Float16* k2b = k2 + bh * 1024 * 64;
    const _Float16* relb = rel2 + (size_t)h * 1024 * 64;
    const _Float16* vbb = vb + bh * 64 * 1024;
    float* outb = out + bh * 64 * 1024 + mt0 * 64;
    // Phase 0: stage A-side rows [q | rel] for m = mt0*64 .. +63 (aliases kb_s)
    {
        int r = t >> 2, part = t & 3;
        int n = mt0 * 64 + r;
        const _Float16* src = (part < 2) ? (q2b + (size_t)n * 64 + part * 32)
                                         : (relb + (size_t)n * 64 + (part - 2) * 32);
        _Float16* dst = kb_s + r * 136 + part * 32;
        ((uint4*)dst)[0] = ((const uint4*)src)[0];
        ((uint4*)dst)[1] = ((const uint4*)src)[1];
        ((uint4*)dst)[2] = ((const uint4*)src)[2];
        ((uint4*)dst)[3] = ((const uint4*)src)[3];
    }
    __syncthreads();
    // q fragment as MFMA *B* operand: col=lm -> m = w*16+lm, k = kk*32 + lq*8 + j
    half8 ah[4];
#pragma unroll
    for (int kk = 0; kk < 4; ++kk)
        ah[kk] = *(half8*)&kb_s[(w * 16 + lm) * 136 + kk * 32 + lq * 8];
    f32x4 acco[4];
#pragma unroll
    for (int i = 0; i < 4; ++i) acco[i] = {0.f, 0.f, 0.f, 0.f};
    float mrun = -3e38f, lrun = 0.f;

    for (int kt = 0; kt < 16; ++kt) {
        int n0 = kt * 64;
        __syncthreads();  // prior QK/PV reads of kb_s/v_s done block-wide
        {
            int r = t >> 2, part = t & 3;
            int n = n0 + r;
            const _Float16* src = (part < 2) ? (k2b + (size_t)n * 64 + part * 32)
                                             : (q2b + (size_t)n * 64 + (part - 2) * 32);
            _Float16* dst = kb_s + r * 136 + part * 32;
            ((uint4*)dst)[0] = ((const uint4*)src)[0];
            ((uint4*)dst)[1] = ((const uint4*)src)[1];
            ((uint4*)dst)[2] = ((const uint4*)src)[2];
            ((uint4*)dst)[3] = ((const uint4*)src)[3];
            int vc = (t & 3) * 16;
            const _Float16* vsrc = vbb + (size_t)r * 1024 + n0 + vc;
            _Float16* vdst = v_s + r * 72 + vc;
            ((uint4*)vdst)[0] = ((const uint4*)vsrc)[0];
            ((uint4*)vdst)[1] = ((const uint4*)vsrc)[1];
        }
        __syncthreads();
        // S^T[n][m]: sac[ct][reg] -> n = ct*16 + lq*4 + reg, m = w*16 + lm
        f32x4 sac[4];
#pragma unroll
        for (int ct = 0; ct < 4; ++ct) sac[ct] = {0.f, 0.f, 0.f, 0.f};
#pragma unroll
        for (int ct = 0; ct < 4; ++ct) {
            half8 kf[4];
#pragma unroll
            for (int kk = 0; kk < 4; ++kk)
                kf[kk] = *(half8*)&kb_s[(ct * 16 + lm) * 136 + kk * 32 + lq * 8];
#pragma unroll
            for (int kk = 0; kk < 4; ++kk)
                sac[ct] = __builtin_amdgcn_mfma_f32_16x16x32_f16(kf[kk], ah[kk], sac[ct], 0, 0, 0);
        }
        // online softmax over n for column m (per-lane; lq-replicated via 2 shuffles)
        float mx = -3e38f;
#pragma unroll
        for (int ct = 0; ct < 4; ++ct)
#pragma unroll
            for (int reg = 0; reg < 4; ++reg) mx = fmaxf(mx, sac[ct][reg]);
        mx = fmaxf(mx, __shfl_xor(mx, 16));
        mx = fmaxf(mx, __shfl_xor(mx, 32));
        float mnew = fmaxf(mrun, mx);
        float al_ = __expf(mrun - mnew);
        float ps[4][4];
        float rs = 0.f;
#pragma unroll
        for (int ct = 0; ct < 4; ++ct)
#pragma unroll
            for (int reg = 0; reg < 4; ++reg) {
                float p = __expf(sac[ct][reg] - mnew);
                ps[ct][reg] = p;
                rs += p;
            }
        rs += __shfl_xor(rs, 16);
        rs += __shfl_xor(rs, 32);
        lrun = lrun * al_ + rs;
        mrun = mnew;
#pragma unroll
        for (int dt = 0; dt < 4; ++dt) {
            acco[dt][0] *= al_; acco[dt][1] *= al_;
            acco[dt][2] *= al_; acco[dt][3] *= al_;
        }
        // store P rows [m][n] (wave-private rows m = w*16 + 0..15): b64 per ct
#pragma unroll
        for (int ct = 0; ct < 4; ++ct) {
            half4 o;
            o[0] = (_Float16)ps[ct][0]; o[1] = (_Float16)ps[ct][1];
            o[2] = (_Float16)ps[ct][2]; o[3] = (_Float16)ps[ct][3];
            *(half4*)&p_s[(w * 16 + lm) * 72 + ct * 16 + lq * 4] = o;
        }
        // PV: out^T[d][m] += v[d][n] * P^T[n][m]
        half8 pfr[2];
#pragma unroll
        for (int ch = 0; ch < 2; ++ch)
            pfr[ch] = *(half8*)&p_s[(w * 16 + lm) * 72 + ch * 32 + lq * 8];
#pragma unroll
        for (int dt = 0; dt < 4; ++dt) {
            half8 vf0 = *(half8*)&v_s[(dt * 16 + lm) * 72 + lq * 8];
            half8 vf1 = *(half8*)&v_s[(dt * 16 + lm) * 72 + 32 + lq * 8];
            acco[dt] = __builtin_amdgcn_mfma_f32_16x16x32_f16(vf0, pfr[0], acco[dt], 0, 0, 0);
            acco[dt] = __builtin_amdgcn_mfma_f32_16x16x32_f16(vf1, pfr[1], acco[dt], 0, 0, 0);
        }
    }
    float li = 1.f / lrun;
#pragma unroll
    for (int dt = 0; dt < 4; ++dt)
#pragma unroll
        for (int reg = 0; reg < 4; ++reg) {
            int d = dt * 16 + lq * 4 + reg;
            outb[(size_t)d * 1024 + w * 16 + lm] = acco[dt][reg] * li;
        }
}

extern "C" void kernel_launch(void* const* d_in, const int* in_sizes, int n_in,
                              void* d_out, int out_size, void* d_ws, size_t ws_size,
                              hipStream_t stream) {
    const float* x     = (const float*)d_in[0];
    const float* Wq    = (const float*)d_in[1];
    const float* bq    = (const float*)d_in[2];
    const float* Wk    = (const float*)d_in[3];
    const float* bk    = (const float*)d_in[4];
    const float* Wv    = (const float*)d_in[5];
    const float* bv    = (const float*)d_in[6];
    const float* rel_h = (const float*)d_in[7];
    const float* rel_w = (const float*)d_in[8];
    char* ws = (char*)d_ws;
    short* A2      = (short*)(ws);                  //  4,718,592 B
    float* bias2   = (float*)(ws + 4718592);        //      6,144 B -> 4,724,736
    short* xT2     = (short*)(ws + 4724736);        // 25,165,824 B -> 29,890,560
    _Float16* q2   = (_Float16*)(ws + 29890560);    //  8,388,608 B -> 38,279,168
    _Float16* k2   = (_Float16*)(ws + 38279168);    //  8,388,608 B -> 46,667,776
    _Float16* vb   = (_Float16*)(ws + 46667776);    //  8,388,608 B -> 55,056,384
    _Float16* rel2 = (_Float16*)(ws + 55056384);    //  1,048,576 B -> 56,104,960
    float* out = (float*)d_out;

    hipLaunchKernelGGL(k_pack_w,   dim3(384),      dim3(256), 0, stream, Wq, Wk, Wv, bq, bk, bv, A2, bias2);
    hipLaunchKernelGGL(k_prep_x,   dim3(16, 8, 8), dim3(256), 0, stream, x, xT2);
    hipLaunchKernelGGL(k_prep_rel, dim3(256),      dim3(256), 0, stream, rel_h, rel_w, rel2);
    hipLaunchKernelGGL(k_proj,     dim3(8, 12, 8), dim3(256), 0, stream, A2, xT2, bias2, q2, k2, vb);
    hipLaunchKernelGGL(k_attn,     dim3(16, 8, 8), dim3(256), 0, stream, q2, k2, rel2, vb, out);
}